// Round 5
// baseline (44.153 us; speedup 1.0000x reference)
//
#include <hip/hip_runtime.h>

#define BIGV 1.0e6f

__device__ __forceinline__ float wave_max64(float v) {
    #pragma unroll
    for (int s = 32; s > 0; s >>= 1)
        v = fmaxf(v, __shfl_xor(v, s, 64));
    return v;
}

// One block per (b, h), 512 threads = 8 waves. Wave c owns candidate
// offsets k = c + 8*l (k -> off: 0,+1,-1,+2,-2,... |dx| nondecreasing in l).
// Phase 1: scan the wave's nearest valid row unconditionally.
// Phase 2: one-shot threshold (wave max of current minima), ballot the
// need mask, scan only those rows. Sound: a stale threshold only
// over-scans, never under-scans.
// Row scan keeps 4 independent partial minima (2 per target, split by j4
// parity) so the sqrt->fma->min chains of consecutive j4 groups are
// independent -> ~2x ILP on the critical path.
__global__ void imageloss_main(
    const float* __restrict__ gt, const float* __restrict__ pred,
    float* __restrict__ ws)
{
    __shared__ float gt_s[4096];
    __shared__ float pr_s[4096];
    __shared__ float rmg[64];
    __shared__ float rmp[64];
    __shared__ float red1[512];
    __shared__ float red2[512];

    const int blk = blockIdx.x;        // 0..511
    const int b   = blk >> 6;
    const int h   = blk & 63;
    const int tid = threadIdx.x;

    const float* __restrict__ gt_b = gt   + b * 4096;
    const float* __restrict__ pr_b = pred + b * 4096;

    // Stage images to LDS; fold per-row minima (16 lanes per row).
    #pragma unroll
    for (int k = 0; k < 2; ++k) {
        int idx = tid + k * 512;               // float4 index, 16 per row
        float4 vg = ((const float4*)gt_b)[idx];
        float4 vp = ((const float4*)pr_b)[idx];
        ((float4*)gt_s)[idx] = vg;
        ((float4*)pr_s)[idx] = vp;
        float mg = fminf(fminf(vg.x, vg.y), fminf(vg.z, vg.w));
        float mp = fminf(fminf(vp.x, vp.y), fminf(vp.z, vp.w));
        #pragma unroll
        for (int s = 1; s < 16; s <<= 1) {
            mg = fminf(mg, __shfl_xor(mg, s, 64));
            mp = fminf(mp, __shfl_xor(mp, s, 64));
        }
        if ((tid & 15) == 0) {
            rmg[idx >> 4] = mg;
            rmp[idx >> 4] = mp;
        }
    }
    __syncthreads();

    const int w = tid & 63;
    const int c = tid >> 6;                    // wave 0..7
    const float wf = (float)w;

    // Per-lane candidate: lane l holds k = c + 8*l (l < 16).
    const int kcand = c + 8 * w;
    const int offc  = (kcand & 1) ? ((kcand + 1) >> 1) : -(kcand >> 1);
    const int rowc  = h + offc;
    const bool valid = (w < 16) && (kcand <= 126) && ((unsigned)rowc < 64u);
    float LB1 = 3.4e38f, LB2 = 3.4e38f;
    if (valid) {
        const int adx = offc < 0 ? -offc : offc;
        const float dpl = (float)(adx + 1);
        LB1 = dpl * rmp[rowc];   // sound lower bound, pred side
        LB2 = dpl * rmg[rowc];   // gt side
    }

    float m1a = 3.4e38f, m1b = 3.4e38f;   // pred-side partial minima
    float m2a = 3.4e38f, m2b = 3.4e38f;   // gt-side partial minima

    auto scan_row = [&](int lsel) {
        const int ksel = c + 8 * lsel;
        const int offs = (ksel & 1) ? ((ksel + 1) >> 1) : -(ksel >> 1);
        const int i    = h + offs;
        const float dx2 = (float)(offs * offs);
        const float4* __restrict__ pr4 = (const float4*)(pr_s + i * 64);
        const float4* __restrict__ gt4 = (const float4*)(gt_s + i * 64);
        #pragma unroll
        for (int j8 = 0; j8 < 8; ++j8) {
            // Two j4 groups per step, independent accumulator pairs.
            float4 pA = pr4[2 * j8];
            float4 gA = gt4[2 * j8];
            float4 pB = pr4[2 * j8 + 1];
            float4 gB = gt4[2 * j8 + 1];
            #pragma unroll
            for (int t = 0; t < 4; ++t) {
                float jA = (float)(j8 * 8 + t);
                float jB = (float)(j8 * 8 + 4 + t);
                float dyA = wf - jA;
                float dyB = wf - jB;
                float dA  = __builtin_amdgcn_sqrtf(fmaf(dyA, dyA, dx2));
                float dB  = __builtin_amdgcn_sqrtf(fmaf(dyB, dyB, dx2));
                float pa  = (&pA.x)[t], ga = (&gA.x)[t];
                float pb  = (&pB.x)[t], gb = (&gB.x)[t];
                m1a = fminf(m1a, fmaf(dA, pa, pa));
                m2a = fminf(m2a, fmaf(dA, ga, ga));
                m1b = fminf(m1b, fmaf(dB, pb, pb));
                m2b = fminf(m2b, fmaf(dB, gb, gb));
            }
        }
    };

    unsigned long long remaining = __ballot(valid);

    // Phase 1: nearest valid row, unconditional.
    if (remaining) {
        int lsel = (int)__builtin_ctzll(remaining);
        remaining &= remaining - 1;
        scan_row(lsel);
    }

    // One-shot threshold + need mask.
    float m1 = fminf(m1a, m1b);
    float m2 = fminf(m2a, m2b);
    const float T1 = wave_max64(m1);
    const float T2 = wave_max64(m2);
    unsigned long long need = remaining & __ballot((LB1 < T1) || (LB2 < T2));
    while (need) {
        int lsel = (int)__builtin_ctzll(need);
        need &= need - 1;
        scan_row(lsel);
    }
    m1 = fminf(fminf(m1a, m1b), m1);
    m2 = fminf(fminf(m2a, m2b), m2);

    red1[tid] = m1;
    red2[tid] = m2;
    __syncthreads();

    if (tid < 64) {
        float a1 = red1[w];
        float a2 = red2[w];
        #pragma unroll
        for (int q = 1; q < 8; ++q) {
            a1 = fminf(a1, red1[q * 64 + w]);
            a2 = fminf(a2, red2[q * 64 + w]);
        }

        const float g = gt_s[h * 64 + w];
        const float p = pr_s[h * 64 + w];
        const float gth = g + (1.0f - g) * BIGV;
        const float pth = p + (1.0f - p) * BIGV;

        float c1 = gth * a1;   // min_dist contribution
        float c2 = pth * a2;   // min_dist_inv contribution
        float df = g - p;
        float sq = df * df;    // loss contribution

        #pragma unroll
        for (int off = 32; off > 0; off >>= 1) {
            c1 += __shfl_down(c1, off, 64);
            c2 += __shfl_down(c2, off, 64);
            sq += __shfl_down(sq, off, 64);
        }
        if (w == 0) {
            atomicAdd(&ws[0], sq);
            atomicAdd(&ws[1], c1);
            atomicAdd(&ws[2], c2);
        }
    }
}

__global__ void imageloss_final(const float* __restrict__ ws, float* __restrict__ out)
{
    out[0] = ws[0] * (1.0f / 512.0f);
    out[1] = ws[1] * (1.0f / 32768.0f);
    out[2] = ws[2] * (1.0f / 32768.0f);
}

extern "C" void kernel_launch(void* const* d_in, const int* in_sizes, int n_in,
                              void* d_out, int out_size, void* d_ws, size_t ws_size,
                              hipStream_t stream)
{
    const float* gt   = (const float*)d_in[0];
    const float* pred = (const float*)d_in[1];
    float* out = (float*)d_out;
    float* ws  = (float*)d_ws;

    hipMemsetAsync(ws, 0, 3 * sizeof(float), stream);
    imageloss_main<<<512, 512, 0, stream>>>(gt, pred, ws);
    imageloss_final<<<1, 1, 0, stream>>>(ws, out);
}